// Round 7
// baseline (377.591 us; speedup 1.0000x reference)
//
#include <hip/hip_runtime.h>
#include <hip/hip_bf16.h>
#include <math.h>

typedef __attribute__((ext_vector_type(8))) __bf16 bf16x8;
typedef __attribute__((ext_vector_type(4))) float floatx4;
typedef __attribute__((ext_vector_type(8))) unsigned short ushort8;

#define C_EMBD 1024
#define T_SEQ 2048
#define NH 16
#define HD 64

#define WAITV(N) asm volatile("s_waitcnt vmcnt(" #N ")" ::: "memory")
#define WAITL(N) asm volatile("s_waitcnt lgkmcnt(" #N ")" ::: "memory")
// inline-asm LDS read; ordering handled manually (WAITL(0)+sched_barrier(0)
// before consuming MFMAs, rule #18).
#define DSR(d, a, OFF) \
  asm volatile("ds_read_b128 %0, %1 offset:" #OFF : "=v"(d) : "v"(a))

static __device__ __forceinline__ unsigned short f2b(float f) {
  __hip_bfloat16 h = __float2bfloat16(f);
  unsigned short u;
  __builtin_memcpy(&u, &h, sizeof(u));
  return u;
}
static __device__ __forceinline__ float b2f(unsigned short u) {
  unsigned int b = ((unsigned int)u) << 16;
  float f;
  __builtin_memcpy(&f, &b, sizeof(f));
  return f;
}

// async global->LDS, 16B per lane; lds base wave-uniform, lane i -> base + i*16
static __device__ __forceinline__ void gload16(const void* g, void* l) {
  __builtin_amdgcn_global_load_lds(
      (__attribute__((address_space(1))) void*)(void*)g,
      (__attribute__((address_space(3))) void*)l, 16, 0, 0);
}

static __device__ __forceinline__ floatx4 mfma_bf16(bf16x8 a, bf16x8 b, floatx4 c) {
  return __builtin_amdgcn_mfma_f32_16x16x32_bf16(a, b, c, 0, 0, 0);
}

static __device__ __forceinline__ unsigned int lds_addr(const void* p) {
  return (unsigned int)(size_t)(__attribute__((address_space(3))) void*)(void*)p;
}

// ---------------- weight transpose: fp32 [K][N] -> bf16 [N][K] ----------------
__global__ __launch_bounds__(256) void wtrans(const float* __restrict__ in,
                                              unsigned short* __restrict__ out,
                                              int K, int N) {
  __shared__ float t[32][33];
  int n0 = blockIdx.x * 32, k0 = blockIdx.y * 32;
  int tx = threadIdx.x & 31, ty = threadIdx.x >> 5;
#pragma unroll
  for (int i = 0; i < 4; i++)
    t[ty + i * 8][tx] = in[(size_t)(k0 + ty + i * 8) * N + n0 + tx];
  __syncthreads();
#pragma unroll
  for (int i = 0; i < 4; i++)
    out[(size_t)(n0 + ty + i * 8) * K + k0 + tx] = f2b(t[tx][ty + i * 8]);
}

// ---------------- layernorm: fp32 row(1024) -> bf16 ----------------
__global__ __launch_bounds__(256) void ln_fwd(const float* __restrict__ x,
                                              const float* __restrict__ g,
                                              const float* __restrict__ bta,
                                              unsigned short* __restrict__ out) {
  int row = blockIdx.x;
  int t = threadIdx.x;
  const float4* xr = (const float4*)(x + (size_t)row * C_EMBD);
  float4 v = xr[t];
  float s = v.x + v.y + v.z + v.w;
  float ss = v.x * v.x + v.y * v.y + v.z * v.z + v.w * v.w;
#pragma unroll
  for (int m = 1; m < 64; m <<= 1) {
    s += __shfl_xor(s, m, 64);
    ss += __shfl_xor(ss, m, 64);
  }
  __shared__ float ps[8];
  int wv = t >> 6;
  if ((t & 63) == 0) { ps[wv] = s; ps[4 + wv] = ss; }
  __syncthreads();
  s = ps[0] + ps[1] + ps[2] + ps[3];
  ss = ps[4] + ps[5] + ps[6] + ps[7];
  float mu = s * (1.0f / C_EMBD);
  float var = ss * (1.0f / C_EMBD) - mu * mu;
  float rs = rsqrtf(var + 1e-5f);
  float4 gv = ((const float4*)g)[t];
  float4 bv = ((const float4*)bta)[t];
  ushort4 o;
  o.x = f2b((v.x - mu) * rs * gv.x + bv.x);
  o.y = f2b((v.y - mu) * rs * gv.y + bv.y);
  o.z = f2b((v.z - mu) * rs * gv.z + bv.z);
  o.w = f2b((v.w - mu) * rs * gv.w + bv.w);
  *(ushort4*)(out + (size_t)row * C_EMBD + t * 4) = o;
}

// ---------------- legacy GEMM (kept for proj: M=4096,N=1024,K=1024) ----------------
template <int EP, int MI>
__global__ __launch_bounds__(256) void gemm_bt(const unsigned short* __restrict__ A,
                                               const unsigned short* __restrict__ Bt,
                                               const float* __restrict__ bias,
                                               const float* __restrict__ res,
                                               void* __restrict__ outv,
                                               unsigned short* __restrict__ vt,
                                               int M, int N, int K) {
  __shared__ __align__(16) unsigned short As[MI * 32 * 32];
  __shared__ __align__(16) unsigned short Bs[128 * 32];
  const int tid = threadIdx.x;
  const int wv = tid >> 6, ln = tid & 63;
  const int quad = ln >> 4, l15 = ln & 15;
  const int wm = wv >> 1, wn = wv & 1;
  const int m0 = blockIdx.y * (MI * 32), n0 = blockIdx.x * 128;

  floatx4 acc[MI][4];
#pragma unroll
  for (int i = 0; i < MI; i++)
#pragma unroll
    for (int j = 0; j < 4; j++) acc[i][j] = (floatx4)0.0f;

  const int rowA = ln >> 2;
  const int koff = (ln & 3) * 8;

  for (int k0 = 0; k0 < K; k0 += 32) {
    if (k0) __syncthreads();
#pragma unroll
    for (int hh = 0; hh < MI / 2; ++hh) {
      int r = hh * 64 + wv * 16 + rowA;
      gload16(A + (size_t)(m0 + r) * K + k0 + koff, &As[(hh * 64 + wv * 16) * 32]);
    }
#pragma unroll
    for (int hh = 0; hh < 2; ++hh) {
      int r = hh * 64 + wv * 16 + rowA;
      gload16(Bt + (size_t)(n0 + r) * K + k0 + koff, &Bs[(hh * 64 + wv * 16) * 32]);
    }
    __syncthreads();
    bf16x8 af[MI], bfr[4];
#pragma unroll
    for (int mi = 0; mi < MI; mi++)
      af[mi] = *(const bf16x8*)&As[(wm * (MI * 16) + mi * 16 + l15) * 32 + quad * 8];
#pragma unroll
    for (int ni = 0; ni < 4; ni++)
      bfr[ni] = *(const bf16x8*)&Bs[(wn * 64 + ni * 16 + l15) * 32 + quad * 8];
#pragma unroll
    for (int mi = 0; mi < MI; mi++)
#pragma unroll
      for (int ni = 0; ni < 4; ni++)
        acc[mi][ni] = mfma_bf16(af[mi], bfr[ni], acc[mi][ni]);
  }

#pragma unroll
  for (int mi = 0; mi < MI; mi++) {
#pragma unroll
    for (int ni = 0; ni < 4; ni++) {
      int col = n0 + wn * 64 + ni * 16 + l15;
      int rowb = m0 + wm * (MI * 16) + mi * 16 + quad * 4;
      float bc = bias[col];
      if (EP == 1) {
#pragma unroll
        for (int r = 0; r < 4; r++) {
          size_t idx = (size_t)(rowb + r) * N + col;
          ((float*)outv)[idx] = acc[mi][ni][r] + bc + res[idx];
        }
      }
    }
  }
}

// ---------------- 256x256 GEMM v6: m201-cadence 4-phase schedule ----------------
// BK=64, 8 waves (2M x 4N), per-wave 128x64, acc[8][4], 2-deep LDS dbuf (128 KiB).
// LDS layout [row][chunk ^ (row&7)] (16B chunks, 128B rows) — proven 0-conflict
// (round 6). Staged via source-chunk permute q=(ln&7)^(ln>>3), LINEAR dest.
// Schedule per K-tile (m201 template): 4 phases; phase p owns acc rows 2p,2p+1.
//   phase p: {4 ds_read A (+8 B in p0), issued BEFORE the opening barrier so
//   LDS latency hides under the rendezvous; stage half of tile t+1 in p0/p1;
//   s_barrier; lgkmcnt(0); sched_barrier; setprio(1); 16 MFMA; setprio(0);
//   s_barrier}. Tile top: WAITV(0) (issued >=2 phases earlier -> ~free) + bar.
// EP: 1=+bias+res->fp32; 2=+bias,GELU->bf16; 3=QKV split; 4=split-K.
template <int EP>
__global__ __launch_bounds__(512, 2) void gemm256(
    const unsigned short* __restrict__ A, const unsigned short* __restrict__ Bt,
    const float* __restrict__ bias, const float* __restrict__ res,
    void* __restrict__ outv, unsigned short* __restrict__ vt,
    float* __restrict__ p0, float* __restrict__ p12,
    int M, int N, int ldK, int KCH) {
  __shared__ __align__(16) unsigned short As[2][16384];
  __shared__ __align__(16) unsigned short Bs[2][16384];
  const int tid = threadIdx.x;
  const int wv = tid >> 6, ln = tid & 63;
  const int quad = ln >> 4, l15 = ln & 15;
  const int wm = wv >> 2, wn = wv & 3;

  // bijective XCD chunk swizzle within a z-slice (nwg % 8 == 0 for all grids)
  const int gx = gridDim.x;
  const int nwg = gx * gridDim.y;
  int id = blockIdx.y * gx + blockIdx.x;
  const int cpx = nwg >> 3;
  id = (id & 7) * cpx + (id >> 3);
  const int n0 = (id % gx) * 256;
  const int m0 = (id / gx) * 256;
  const int bz = blockIdx.z;

  A += (size_t)bz * KCH;
  Bt += (size_t)bz * KCH;

  // staging: gload g covers rows [g*64 + wv*8, +8); lane ln -> row += ln>>3,
  // source chunk (ln&7)^(ln>>3) (128B-contiguous per 8-lane group).
  const unsigned short* aSt =
      A + (size_t)(m0 + wv * 8 + (ln >> 3)) * ldK + (((ln & 7) ^ (ln >> 3)) * 8);
  const unsigned short* bSt =
      Bt + (size_t)(n0 + wv * 8 + (ln >> 3)) * ldK + (((ln & 7) ^ (ln >> 3)) * 8);
  const size_t gstep = (size_t)64 * ldK;

  // fragment-read LDS byte addresses: row stride 128B, slot = chunk^(row&7),
  // chunk = kc*4+quad, row&7 = l15&7 (row bases are multiples of 16).
  const int sw0 = ((quad) ^ (l15 & 7)) * 16;
  const int sw1 = ((4 + quad) ^ (l15 & 7)) * 16;
  const unsigned int aoff0 = lds_addr(&As[0][0]) + (wm * 128 + l15) * 128 + sw0;
  const unsigned int aoff1 = lds_addr(&As[0][0]) + (wm * 128 + l15) * 128 + sw1;
  const unsigned int boff0 = lds_addr(&Bs[0][0]) + (wn * 64 + l15) * 128 + sw0;
  const unsigned int boff1 = lds_addr(&Bs[0][0]) + (wn * 64 + l15) * 128 + sw1;

  floatx4 acc[8][4];
#pragma unroll
  for (int i = 0; i < 8; i++)
#pragma unroll
    for (int j = 0; j < 4; j++) acc[i][j] = (floatx4)0.0f;

  const int NT = KCH >> 6;

  auto stA1 = [&](int bi, int kt, int g) {
    gload16(aSt + (size_t)kt * 64 + (size_t)g * gstep,
            &As[bi][(g * 64 + wv * 8) * 64]);
  };
  auto stB1 = [&](int bi, int kt, int g) {
    gload16(bSt + (size_t)kt * 64 + (size_t)g * gstep,
            &Bs[bi][(g * 64 + wv * 8) * 64]);
  };

  // prologue: stage tile 0 fully
  stA1(0, 0, 0); stA1(0, 0, 1); stA1(0, 0, 2); stA1(0, 0, 3);
  stB1(0, 0, 0); stB1(0, 0, 1); stB1(0, 0, 2); stB1(0, 0, 3);

  for (int t = 0; t < NT; ++t) {
    const int cur = t & 1;
    const bool more = (t + 1 < NT);
    const unsigned int ab0 = aoff0 + (cur << 15), ab1 = aoff1 + (cur << 15);
    const unsigned int bb0 = boff0 + (cur << 15), bb1 = boff1 + (cur << 15);

    WAITV(0);  // tile t's stages landed (issued >=2 phases before this point)
    __builtin_amdgcn_s_barrier();

    bf16x8 bf0[4], bf1[4];
    {  // phase 0: B (8 reads) + A rows 0,1 (4 reads); stage A(t+1)
      bf16x8 a0, a1, a2, a3;
      DSR(bf0[0], bb0, 0);    DSR(bf0[1], bb0, 2048);
      DSR(bf0[2], bb0, 4096); DSR(bf0[3], bb0, 6144);
      DSR(bf1[0], bb1, 0);    DSR(bf1[1], bb1, 2048);
      DSR(bf1[2], bb1, 4096); DSR(bf1[3], bb1, 6144);
      DSR(a0, ab0, 0); DSR(a1, ab0, 2048);
      DSR(a2, ab1, 0); DSR(a3, ab1, 2048);
      if (more) {
        stA1(cur ^ 1, t + 1, 0); stA1(cur ^ 1, t + 1, 1);
        stA1(cur ^ 1, t + 1, 2); stA1(cur ^ 1, t + 1, 3);
      }
      WAITL(8);
      __builtin_amdgcn_s_barrier();
      WAITL(0);
      __builtin_amdgcn_sched_barrier(0);
      __builtin_amdgcn_s_setprio(1);
#pragma unroll
      for (int ni = 0; ni < 4; ni++) {
        acc[0][ni] = mfma_bf16(a0, bf0[ni], acc[0][ni]);
        acc[0][ni] = mfma_bf16(a2, bf1[ni], acc[0][ni]);
        acc[1][ni] = mfma_bf16(a1, bf0[ni], acc[1][ni]);
        acc[1][ni] = mfma_bf16(a3, bf1[ni], acc[1][ni]);
      }
      __builtin_amdgcn_s_setprio(0);
      __builtin_amdgcn_s_barrier();
    }
    {  // phase 1: A rows 2,3; stage B(t+1)
      bf16x8 a0, a1, a2, a3;
      DSR(a0, ab0, 4096); DSR(a1, ab0, 6144);
      DSR(a2, ab1, 4096); DSR(a3, ab1, 6144);
      if (more) {
        stB1(cur ^ 1, t + 1, 0); stB1(cur ^ 1, t + 1, 1);
        stB1(cur ^ 1, t + 1, 2); stB1(cur ^ 1, t + 1, 3);
      }
      __builtin_amdgcn_s_barrier();
      WAITL(0);
      __builtin_amdgcn_sched_barrier(0);
      __builtin_amdgcn_s_setprio(1);
#pragma unroll
      for (int ni = 0; ni < 4; ni++) {
        acc[2][ni] = mfma_bf16(a0, bf0[ni], acc[2][ni]);
        acc[2][ni] = mfma_bf16(a2, bf1[ni], acc[2][ni]);
        acc[3][ni] = mfma_bf16(a1, bf0[ni], acc[3][ni]);
        acc[3][ni] = mfma_bf16(a3, bf1[ni], acc[3][ni]);
      }
      __builtin_amdgcn_s_setprio(0);
      __builtin_amdgcn_s_barrier();
    }
    {  // phase 2: A rows 4,5
      bf16x8 a0, a1, a2, a3;
      DSR(a0, ab0, 8192); DSR(a1, ab0, 10240);
      DSR(a2, ab1, 8192); DSR(a3, ab1, 10240);
      __builtin_amdgcn_s_barrier();
      WAITL(0);
      __builtin_amdgcn_sched_barrier(0);
      __builtin_amdgcn_s_setprio(1);
#pragma unroll
      for (int ni = 0; ni < 4; ni++) {
        acc[4][ni] = mfma_bf16(a0, bf0[ni], acc[4][ni]);
        acc[4][ni] = mfma_bf16(a2, bf1[ni], acc[4][ni]);
        acc[5][ni] = mfma_bf16(a1, bf0[ni], acc[5][ni]);
        acc[5][ni] = mfma_bf16(a3, bf1[ni], acc[5][ni]);
      }
      __builtin_amdgcn_s_setprio(0);
      __builtin_amdgcn_s_barrier();
    }
    {  // phase 3: A rows 6,7
      bf16x8 a0, a1, a2, a3;
      DSR(a0, ab0, 12288); DSR(a1, ab0, 14336);
      DSR(a2, ab1, 12288); DSR(a3, ab1, 14336);
      __builtin_amdgcn_s_barrier();
      WAITL(0);
      __builtin_amdgcn_sched_barrier(0);
      __builtin_amdgcn_s_setprio(1);
#pragma unroll
      for (int ni = 0; ni < 4; ni++) {
        acc[6][ni] = mfma_bf16(a0, bf0[ni], acc[6][ni]);
        acc[6][ni] = mfma_bf16(a2, bf1[ni], acc[6][ni]);
        acc[7][ni] = mfma_bf16(a1, bf0[ni], acc[7][ni]);
        acc[7][ni] = mfma_bf16(a3, bf1[ni], acc[7][ni]);
      }
      __builtin_amdgcn_s_setprio(0);
      __builtin_amdgcn_s_barrier();
    }
  }

#pragma unroll
  for (int mi = 0; mi < 8; mi++) {
#pragma unroll
    for (int ni = 0; ni < 4; ni++) {
      const int col = n0 + wn * 64 + ni * 16 + l15;
      const int rowb = m0 + wm * 128 + mi * 16 + quad * 4;
      const float bc = bias ? bias[col] : 0.0f;
      if (EP == 1) {
#pragma unroll
        for (int r = 0; r < 4; r++) {
          size_t idx = (size_t)(rowb + r) * N + col;
          ((float*)outv)[idx] = acc[mi][ni][r] + bc + res[idx];
        }
      } else if (EP == 2) {
#pragma unroll
        for (int r = 0; r < 4; r++) {
          float v = acc[mi][ni][r] + bc;
          v = 0.5f * v * (1.0f + erff(v * 0.70710678118f));
          ((unsigned short*)outv)[(size_t)(rowb + r) * N + col] = f2b(v);
        }
      } else if (EP == 3) {  // QKV split
        if (col < 2048) {
#pragma unroll
          for (int r = 0; r < 4; r++)
            ((unsigned short*)outv)[(size_t)(rowb + r) * N + col] =
                f2b(acc[mi][ni][r] + bc);
        } else {
          int dall = col - 2048;
          int hh2 = dall >> 6, dd = dall & 63;
          int bq = rowb >> 11, t0 = rowb & 2047;
          __align__(8) unsigned short pk[4];
#pragma unroll
          for (int r = 0; r < 4; r++) pk[r] = f2b(acc[mi][ni][r] + bc);
          *(ushort4*)&vt[(size_t)((bq * NH + hh2) * HD + dd) * T_SEQ + t0] =
              *(const ushort4*)pk;
        }
      } else {  // EP == 4: split-K
        if (bz == 3) {
#pragma unroll
          for (int r = 0; r < 4; r++) {
            size_t idx = (size_t)(rowb + r) * N + col;
            ((float*)outv)[idx] = acc[mi][ni][r] + bc + res[idx];
          }
        } else {
          const size_t MN = (size_t)M * N;
          float* pp = (bz == 0) ? p0 : p12 + (size_t)(bz - 1) * MN;
#pragma unroll
          for (int r = 0; r < 4; r++)
            pp[(size_t)(rowb + r) * N + col] = acc[mi][ni][r];
        }
      }
    }
  }
}

// ---------------- split-K partial reduce: out += p0 + p12[0] + p12[1] ----------------
__global__ __launch_bounds__(256) void red3(const float* __restrict__ p0,
                                            const float* __restrict__ p12,
                                            float* __restrict__ out) {
  const size_t MN4 = (size_t)4096 * 1024 / 4;
  for (size_t i = (size_t)blockIdx.x * 256 + threadIdx.x; i < MN4;
       i += (size_t)gridDim.x * 256) {
    float4 a = ((const float4*)p0)[i];
    float4 b = ((const float4*)p12)[i];
    float4 c = ((const float4*)p12)[i + MN4];
    float4 o = ((float4*)out)[i];
    o.x += a.x + b.x + c.x;
    o.y += a.y + b.y + c.y;
    o.z += a.z + b.z + c.z;
    o.w += a.w + b.w + c.w;
    ((float4*)out)[i] = o;
  }
}

// ---------------- flash attention (causal), D=64, operand-swapped ----------------
// triple-buffered K/V in LDS, counted vmcnt, ONE raw s_barrier per step.
__global__ __launch_bounds__(256) void attn_fwd(const unsigned short* __restrict__ qkv,
                                                const unsigned short* __restrict__ vt,
                                                unsigned short* __restrict__ y) {
  __shared__ __align__(16) unsigned short Ks[3][64 * 64];
  __shared__ __align__(16) unsigned short Vs[3][64 * 64];
  __shared__ __align__(16) unsigned short Ps[4 * 16 * 72];
  const int tid = threadIdx.x;
  const int wv = tid >> 6, ln = tid & 63;
  const int quad = ln >> 4, l15 = ln & 15;
  const int pair = blockIdx.x, h = blockIdx.y, b = blockIdx.z;
  unsigned short* Pw = &Ps[wv * 16 * 72];

  const unsigned short* kbase = qkv + (size_t)b * T_SEQ * 3072 + 1024 + h * HD;
  const unsigned short* vbase = vt + (size_t)(b * NH + h) * HD * T_SEQ;

  int koffs[2], voffs[2], ldst[2];
#pragma unroll
  for (int g = 0; g < 2; g++) {
    int S = wv * 128 + g * 64 + ln;
    int r = S >> 3;
    int c = (S & 7) ^ (r & 7);
    koffs[g] = r * 3072 + c * 8;
    voffs[g] = r * T_SEQ + c * 8;
    ldst[g] = wv * 1024 + g * 512;
  }

  auto stage = [&](int kt, int slot) {
#pragma unroll
    for (int g = 0; g < 2; g++) {
      gload16(kbase + (size_t)(kt * 64) * 3072 + koffs[g], &Ks[slot][ldst[g]]);
      gload16(vbase + kt * 64 + voffs[g], &Vs[slot][ldst[g]]);
    }
  };

  for (int ph = 0; ph < 2; ++ph) {
    const int qt = ph ? (31 - pair) : pair;
    const unsigned short* qp =
        qkv + (size_t)(b * T_SEQ + qt * 64 + wv * 16 + l15) * 3072 + h * HD;
    bf16x8 qf[2];
#pragma unroll
    for (int kc = 0; kc < 2; kc++) {
      ushort8 u = *(const ushort8*)(qp + kc * 32 + quad * 8);
      union { ushort8 u; bf16x8 v; } cv;
#pragma unroll
      for (int j = 0; j < 8; j++) cv.u[j] = f2b(b2f(u[j]) * 0.18033688f);
      qf[kc] = cv.v;
    }

    floatx4 o[4];
#pragma unroll
    for (int dt = 0; dt < 4; dt++) o[dt] = (floatx4)0.0f;
    float lacc = 0.0f;

    stage(0, 0);
    if (qt >= 1) stage(1, 1);

    for (int kt = 0; kt <= qt; ++kt) {
      const int slot = kt % 3;
      const bool diag = (kt == qt);
      if (kt < qt) WAITV(4); else WAITV(0);
      __builtin_amdgcn_s_barrier();
      if (kt + 2 <= qt) stage(kt + 2, (kt + 2) % 3);

      const unsigned short* Kc = Ks[slot];
      const unsigned short* Vc = Vs[slot];
      floatx4 s[4];
#pragma unroll
      for (int nt = 0; nt < 4; nt++) s[nt] = (floatx4)0.0f;
#pragma unroll
      for (int nt = 0; nt < 4; nt++)
#pragma unroll
        for (int kc = 0; kc < 2; kc++) {
          bf16x8 kf = *(const bf16x8*)
              &Kc[(nt * 16 + l15) * 64 + (((kc * 4 + quad) ^ (l15 & 7)) * 8)];
          s[nt] = mfma_bf16(kf, qf[kc], s[nt]);
        }

      float psum = 0.0f;
#pragma unroll
      for (int nt = 0; nt < 4; nt++) {
        __align__(8) unsigned short pk[4];
#pragma unroll
        for (int r = 0; r < 4; r++) {
          float sv = s[nt][r];
          if (diag && (nt * 16 + quad * 4 + r > wv * 16 + l15)) sv = -1e30f;
          float p = exp2f(sv - 12.0f);
          psum += p;
          pk[r] = f2b(p);
        }
        *(ushort4*)&Pw[l15 * 72 + nt * 16 + quad * 4] = *(const ushort4*)pk;
      }
      lacc += psum;

      bf16x8 pf0 = *(const bf16x8*)&Pw[l15 * 72 + quad * 8];
      bf16x8 pf1 = *(const bf16x8*)&Pw[l15 * 72 + 32 + quad * 8];
#pragma unroll
      for (int dt = 0; dt < 4; dt++) {
        bf16x8 vf0 = *(const bf16x8*)
            &Vc[(dt * 16 + l15) * 64 + ((quad ^ (l15 & 7)) * 8)];
        bf16x8 vf1 = *(const bf16x8*)
            &Vc[(dt * 16 + l15) * 64 + (((4 + quad) ^ (l15 & 7)) * 8)];
        o[dt] = mfma_bf16(vf0, pf0, o[dt]);
        o[dt] = mfma_bf16(vf1, pf1, o[dt]);
      }
    }

    lacc += __shfl_xor(lacc, 16, 64);
    lacc += __shfl_xor(lacc, 32, 64);
    float rinv = 1.0f / lacc;
#pragma unroll
    for (int dt = 0; dt < 4; dt++) {
      __align__(8) unsigned short ov[4];
#pragma unroll
      for (int r = 0; r < 4; r++) ov[r] = f2b(o[dt][r] * rinv);
      *(ushort4*)&y[(size_t)(b * T_SEQ + qt * 64 + wv * 16 + l15) * C_EMBD +
                    h * HD + dt * 16 + quad * 4] = *(const ushort4*)ov;
    }
  }
}

extern "C" void kernel_launch(void* const* d_in, const int* in_sizes, int n_in,
                              void* d_out, int out_size, void* d_ws, size_t ws_size,
                              hipStream_t stream) {
  (void)in_sizes; (void)n_in; (void)out_size; (void)ws_size;
  const float* x      = (const float*)d_in[0];
  const float* ln1_g  = (const float*)d_in[1];
  const float* ln1_b  = (const float*)d_in[2];
  const float* w_attn = (const float*)d_in[3];
  const float* b_attn = (const float*)d_in[4];
  const float* w_proj = (const float*)d_in[5];
  const float* b_proj = (const float*)d_in[6];
  const float* ln2_g  = (const float*)d_in[7];
  const float* ln2_b  = (const float*)d_in[8];
  const float* w_fc   = (const float*)d_in[9];
  const float* b_fc   = (const float*)d_in[10];
  const float* w_fc2  = (const float*)d_in[11];
  const float* b_fc2  = (const float*)d_in[12];
  float* out = (float*)d_out;  // also serves as x1 (post-attention residual)

  char* wsb = (char*)d_ws;
  char* ws = wsb;
  unsigned short* wat  = (unsigned short*)ws; ws += (size_t)3072 * 1024 * 2;  // [0,6M)
  unsigned short* wpt  = (unsigned short*)ws; ws += (size_t)1024 * 1024 * 2;  // [6,8M)
  unsigned short* wft  = (unsigned short*)ws; ws += (size_t)4096 * 1024 * 2;  // [8,16M)
  unsigned short* wf2t = (unsigned short*)ws; ws += (size_t)1024 * 4096 * 2;  // [16,24M) LIVE in FC2
  unsigned short* xn   = (unsigned short*)ws; ws += (size_t)4096 * 1024 * 2;  // [24,32M)
  unsigned short* qkv  = (unsigned short*)ws; ws += (size_t)4096 * 3072 * 2;  // [32,56M)
  unsigned short* yat  = (unsigned short*)ws; ws += (size_t)4096 * 1024 * 2;  // [56,64M)
  unsigned short* hbuf = (unsigned short*)ws; ws += (size_t)4096 * 4096 * 2;  // [64,96M) LIVE in FC2
  // V^T (8 MB) aliases hbuf: vt live QKV-gemm -> attn; hbuf live FC -> FC2.
  unsigned short* vt = hbuf;
  // FC2 split-K partials alias regions dead by FC2 time:
  // p0  (16MB) over wat+wpt+wft; p12 (32MB) over xn+qkv.
  float* p0  = (float*)wsb;
  float* p12 = (float*)(wsb + (size_t)24 * 1024 * 1024);

  wtrans<<<dim3(3072 / 32, 1024 / 32), 256, 0, stream>>>(w_attn, wat, 1024, 3072);
  wtrans<<<dim3(1024 / 32, 1024 / 32), 256, 0, stream>>>(w_proj, wpt, 1024, 1024);
  wtrans<<<dim3(4096 / 32, 1024 / 32), 256, 0, stream>>>(w_fc, wft, 1024, 4096);
  wtrans<<<dim3(1024 / 32, 4096 / 32), 256, 0, stream>>>(w_fc2, wf2t, 4096, 1024);

  ln_fwd<<<4096, 256, 0, stream>>>(x, ln1_g, ln1_b, xn);
  gemm256<3><<<dim3(3072 / 256, 4096 / 256), 512, 0, stream>>>(
      xn, wat, b_attn, nullptr, qkv, vt, nullptr, nullptr, 4096, 3072, 1024, 1024);
  attn_fwd<<<dim3(16, NH, 2), 256, 0, stream>>>(qkv, vt, yat);
  gemm_bt<1, 2><<<dim3(8, 64), 256, 0, stream>>>(
      yat, wpt, b_proj, x, out, nullptr, 4096, 1024, 1024);
  ln_fwd<<<4096, 256, 0, stream>>>(out, ln2_g, ln2_b, xn);
  gemm256<2><<<dim3(4096 / 256, 4096 / 256), 512, 0, stream>>>(
      xn, wft, b_fc, nullptr, hbuf, nullptr, nullptr, nullptr, 4096, 4096, 1024, 1024);
  gemm256<4><<<dim3(1024 / 256, 4096 / 256, 4), 512, 0, stream>>>(
      hbuf, wf2t, b_fc2, out, out, nullptr, p0, p12, 4096, 1024, 4096, 1024);
  red3<<<2048, 256, 0, stream>>>(p0, p12, out);
}

// Round 8
// 367.880 us; speedup vs baseline: 1.0264x; 1.0264x over previous
//
#include <hip/hip_runtime.h>
#include <hip/hip_bf16.h>
#include <math.h>

typedef __attribute__((ext_vector_type(8))) __bf16 bf16x8;
typedef __attribute__((ext_vector_type(4))) float floatx4;
typedef __attribute__((ext_vector_type(8))) unsigned short ushort8;

#define C_EMBD 1024
#define T_SEQ 2048
#define NH 16
#define HD 64

#define WAITV(N) asm volatile("s_waitcnt vmcnt(" #N ")" ::: "memory")
#define WAITL(N) asm volatile("s_waitcnt lgkmcnt(" #N ")" ::: "memory")
// inline-asm LDS read; ordering handled manually (WAITL(0)+sched_barrier(0)
// before consuming MFMAs, rule #18).
#define DSR(d, a, OFF) \
  asm volatile("ds_read_b128 %0, %1 offset:" #OFF : "=v"(d) : "v"(a))

static __device__ __forceinline__ unsigned short f2b(float f) {
  __hip_bfloat16 h = __float2bfloat16(f);
  unsigned short u;
  __builtin_memcpy(&u, &h, sizeof(u));
  return u;
}
static __device__ __forceinline__ float b2f(unsigned short u) {
  unsigned int b = ((unsigned int)u) << 16;
  float f;
  __builtin_memcpy(&f, &b, sizeof(f));
  return f;
}

// async global->LDS, 16B per lane; lds base wave-uniform, lane i -> base + i*16
static __device__ __forceinline__ void gload16(const void* g, void* l) {
  __builtin_amdgcn_global_load_lds(
      (__attribute__((address_space(1))) void*)(void*)g,
      (__attribute__((address_space(3))) void*)l, 16, 0, 0);
}

static __device__ __forceinline__ floatx4 mfma_bf16(bf16x8 a, bf16x8 b, floatx4 c) {
  return __builtin_amdgcn_mfma_f32_16x16x32_bf16(a, b, c, 0, 0, 0);
}

static __device__ __forceinline__ unsigned int lds_addr(const void* p) {
  return (unsigned int)(size_t)(__attribute__((address_space(3))) void*)(void*)p;
}

// ---------------- weight transpose: fp32 [K][N] -> bf16 [N][K] ----------------
__global__ __launch_bounds__(256) void wtrans(const float* __restrict__ in,
                                              unsigned short* __restrict__ out,
                                              int K, int N) {
  __shared__ float t[32][33];
  int n0 = blockIdx.x * 32, k0 = blockIdx.y * 32;
  int tx = threadIdx.x & 31, ty = threadIdx.x >> 5;
#pragma unroll
  for (int i = 0; i < 4; i++)
    t[ty + i * 8][tx] = in[(size_t)(k0 + ty + i * 8) * N + n0 + tx];
  __syncthreads();
#pragma unroll
  for (int i = 0; i < 4; i++)
    out[(size_t)(n0 + ty + i * 8) * K + k0 + tx] = f2b(t[tx][ty + i * 8]);
}

// ---------------- layernorm: fp32 row(1024) -> bf16 ----------------
__global__ __launch_bounds__(256) void ln_fwd(const float* __restrict__ x,
                                              const float* __restrict__ g,
                                              const float* __restrict__ bta,
                                              unsigned short* __restrict__ out) {
  int row = blockIdx.x;
  int t = threadIdx.x;
  const float4* xr = (const float4*)(x + (size_t)row * C_EMBD);
  float4 v = xr[t];
  float s = v.x + v.y + v.z + v.w;
  float ss = v.x * v.x + v.y * v.y + v.z * v.z + v.w * v.w;
#pragma unroll
  for (int m = 1; m < 64; m <<= 1) {
    s += __shfl_xor(s, m, 64);
    ss += __shfl_xor(ss, m, 64);
  }
  __shared__ float ps[8];
  int wv = t >> 6;
  if ((t & 63) == 0) { ps[wv] = s; ps[4 + wv] = ss; }
  __syncthreads();
  s = ps[0] + ps[1] + ps[2] + ps[3];
  ss = ps[4] + ps[5] + ps[6] + ps[7];
  float mu = s * (1.0f / C_EMBD);
  float var = ss * (1.0f / C_EMBD) - mu * mu;
  float rs = rsqrtf(var + 1e-5f);
  float4 gv = ((const float4*)g)[t];
  float4 bv = ((const float4*)bta)[t];
  ushort4 o;
  o.x = f2b((v.x - mu) * rs * gv.x + bv.x);
  o.y = f2b((v.y - mu) * rs * gv.y + bv.y);
  o.z = f2b((v.z - mu) * rs * gv.z + bv.z);
  o.w = f2b((v.w - mu) * rs * gv.w + bv.w);
  *(ushort4*)(out + (size_t)row * C_EMBD + t * 4) = o;
}

// ---------------- 128x128 GEMM: round-6 cadence + multi-block overlap ----------------
// 4 waves (2M x 2N), per-wave 64x64, acc[4][4], BK=64, 2-deep dbuf = 32 KiB LDS
// -> __launch_bounds__(256,2) gives >=2 blocks/CU: when one block waits on
// vmcnt/barrier, the other block's waves issue MFMA (m114 cross-block overlap)
// — the ingredient 256^2 tiles (grid == CU count) could never have.
// LDS layout [row][chunk ^ (row&7)] (16B chunks, 128B rows) — proven 0-conflict
// (round 6). Staged via source-chunk permute q=(ln&7)^(ln>>3), LINEAR dest.
// Per tile (ONE barrier, the round-6 winner): WAITV(0); s_barrier;
//   {12 ds_read (B all + A rows 0-1) ; stage(t+1) x8} ; lgkm0 ; 16 MFMA ;
//   {4 ds_read (A rows 2-3)} ; lgkm0 ; 16 MFMA.
// Buffer safety: tile t reads buf[t&1]; stage(t+2) (writes buf[t&1]) is issued
// after t+1's top barrier, which all waves pass only after completing t's reads.
// EP: 1=+bias+res->fp32; 2=+bias,GELU->bf16; 3=QKV split; 4=split-K.
template <int EP>
__global__ __launch_bounds__(256, 2) void gemm128(
    const unsigned short* __restrict__ A, const unsigned short* __restrict__ Bt,
    const float* __restrict__ bias, const float* __restrict__ res,
    void* __restrict__ outv, unsigned short* __restrict__ vt,
    float* __restrict__ p0, float* __restrict__ p12,
    int M, int N, int ldK, int KCH) {
  __shared__ __align__(16) unsigned short As[2][8192];
  __shared__ __align__(16) unsigned short Bs[2][8192];
  const int tid = threadIdx.x;
  const int wv = tid >> 6, ln = tid & 63;
  const int quad = ln >> 4, l15 = ln & 15;
  const int wm = wv >> 1, wn = wv & 1;

  // bijective XCD chunk swizzle within a z-slice (nwg % 8 == 0 for all grids)
  const int gx = gridDim.x;
  const int nwg = gx * gridDim.y;
  int id = blockIdx.y * gx + blockIdx.x;
  const int cpx = nwg >> 3;
  id = (id & 7) * cpx + (id >> 3);
  const int n0 = (id % gx) * 128;
  const int m0 = (id / gx) * 128;
  const int bz = blockIdx.z;

  A += (size_t)bz * KCH;
  Bt += (size_t)bz * KCH;

  // staging: call g covers rows [g*32, +32); wave wv rows [g*32+wv*8, +8);
  // lane: row += ln>>3, source chunk (ln&7)^(ln>>3) (dest linear, rule #21).
  const unsigned short* aSt =
      A + (size_t)(m0 + wv * 8 + (ln >> 3)) * ldK + (((ln & 7) ^ (ln >> 3)) * 8);
  const unsigned short* bSt =
      Bt + (size_t)(n0 + wv * 8 + (ln >> 3)) * ldK + (((ln & 7) ^ (ln >> 3)) * 8);
  const size_t gstep = (size_t)32 * ldK;

  // fragment-read LDS byte addresses: row stride 128B, slot = chunk^(row&7),
  // chunk = kc*4+quad, row&7 = l15&7 (row bases are multiples of 16).
  const int sw0 = ((quad) ^ (l15 & 7)) * 16;
  const int sw1 = ((4 + quad) ^ (l15 & 7)) * 16;
  const unsigned int aoff0 = lds_addr(&As[0][0]) + (wm * 64 + l15) * 128 + sw0;
  const unsigned int aoff1 = lds_addr(&As[0][0]) + (wm * 64 + l15) * 128 + sw1;
  const unsigned int boff0 = lds_addr(&Bs[0][0]) + (wn * 64 + l15) * 128 + sw0;
  const unsigned int boff1 = lds_addr(&Bs[0][0]) + (wn * 64 + l15) * 128 + sw1;

  floatx4 acc[4][4];
#pragma unroll
  for (int i = 0; i < 4; i++)
#pragma unroll
    for (int j = 0; j < 4; j++) acc[i][j] = (floatx4)0.0f;

  const int NT = KCH >> 6;

  auto stA1 = [&](int bi, int kt, int g) {
    gload16(aSt + (size_t)kt * 64 + (size_t)g * gstep,
            &As[bi][(g * 32 + wv * 8) * 64]);
  };
  auto stB1 = [&](int bi, int kt, int g) {
    gload16(bSt + (size_t)kt * 64 + (size_t)g * gstep,
            &Bs[bi][(g * 32 + wv * 8) * 64]);
  };

  // prologue: stage tile 0 fully (8 calls)
  stB1(0, 0, 0); stB1(0, 0, 1); stB1(0, 0, 2); stB1(0, 0, 3);
  stA1(0, 0, 0); stA1(0, 0, 1); stA1(0, 0, 2); stA1(0, 0, 3);

  for (int t = 0; t < NT; ++t) {
    const int cur = t & 1;
    const bool more = (t + 1 < NT);
    const unsigned int ab0 = aoff0 + (cur << 14), ab1 = aoff1 + (cur << 14);
    const unsigned int bb0 = boff0 + (cur << 14), bb1 = boff1 + (cur << 14);

    WAITV(0);  // tile t's 8 stages landed (issued >= half a tile earlier)
    __builtin_amdgcn_s_barrier();  // the ONLY rendezvous per tile

    bf16x8 bf0[4], bf1[4], a0, a1, a2, a3;
    DSR(bf0[0], bb0, 0);    DSR(bf0[1], bb0, 2048);
    DSR(bf0[2], bb0, 4096); DSR(bf0[3], bb0, 6144);
    DSR(bf1[0], bb1, 0);    DSR(bf1[1], bb1, 2048);
    DSR(bf1[2], bb1, 4096); DSR(bf1[3], bb1, 6144);
    DSR(a0, ab0, 0); DSR(a1, ab0, 2048);
    DSR(a2, ab1, 0); DSR(a3, ab1, 2048);
    if (more) {
      stB1(cur ^ 1, t + 1, 0); stB1(cur ^ 1, t + 1, 1);
      stB1(cur ^ 1, t + 1, 2); stB1(cur ^ 1, t + 1, 3);
      stA1(cur ^ 1, t + 1, 0); stA1(cur ^ 1, t + 1, 1);
      stA1(cur ^ 1, t + 1, 2); stA1(cur ^ 1, t + 1, 3);
    }
    WAITL(0);
    __builtin_amdgcn_sched_barrier(0);
    __builtin_amdgcn_s_setprio(1);
#pragma unroll
    for (int ni = 0; ni < 4; ni++) {
      acc[0][ni] = mfma_bf16(a0, bf0[ni], acc[0][ni]);
      acc[0][ni] = mfma_bf16(a2, bf1[ni], acc[0][ni]);
      acc[1][ni] = mfma_bf16(a1, bf0[ni], acc[1][ni]);
      acc[1][ni] = mfma_bf16(a3, bf1[ni], acc[1][ni]);
    }
    __builtin_amdgcn_s_setprio(0);

    DSR(a0, ab0, 4096); DSR(a1, ab0, 6144);
    DSR(a2, ab1, 4096); DSR(a3, ab1, 6144);
    WAITL(0);
    __builtin_amdgcn_sched_barrier(0);
    __builtin_amdgcn_s_setprio(1);
#pragma unroll
    for (int ni = 0; ni < 4; ni++) {
      acc[2][ni] = mfma_bf16(a0, bf0[ni], acc[2][ni]);
      acc[2][ni] = mfma_bf16(a2, bf1[ni], acc[2][ni]);
      acc[3][ni] = mfma_bf16(a1, bf0[ni], acc[3][ni]);
      acc[3][ni] = mfma_bf16(a3, bf1[ni], acc[3][ni]);
    }
    __builtin_amdgcn_s_setprio(0);
    // next tile's top barrier separates these reads from buf reuse
  }

#pragma unroll
  for (int mi = 0; mi < 4; mi++) {
#pragma unroll
    for (int ni = 0; ni < 4; ni++) {
      const int col = n0 + wn * 64 + ni * 16 + l15;
      const int rowb = m0 + wm * 64 + mi * 16 + quad * 4;
      const float bc = bias ? bias[col] : 0.0f;
      if (EP == 1) {
#pragma unroll
        for (int r = 0; r < 4; r++) {
          size_t idx = (size_t)(rowb + r) * N + col;
          ((float*)outv)[idx] = acc[mi][ni][r] + bc + res[idx];
        }
      } else if (EP == 2) {
#pragma unroll
        for (int r = 0; r < 4; r++) {
          float v = acc[mi][ni][r] + bc;
          v = 0.5f * v * (1.0f + erff(v * 0.70710678118f));
          ((unsigned short*)outv)[(size_t)(rowb + r) * N + col] = f2b(v);
        }
      } else if (EP == 3) {  // QKV split
        if (col < 2048) {
#pragma unroll
          for (int r = 0; r < 4; r++)
            ((unsigned short*)outv)[(size_t)(rowb + r) * N + col] =
                f2b(acc[mi][ni][r] + bc);
        } else {
          int dall = col - 2048;
          int hh2 = dall >> 6, dd = dall & 63;
          int bq = rowb >> 11, t0 = rowb & 2047;
          __align__(8) unsigned short pk[4];
#pragma unroll
          for (int r = 0; r < 4; r++) pk[r] = f2b(acc[mi][ni][r] + bc);
          *(ushort4*)&vt[(size_t)((bq * NH + hh2) * HD + dd) * T_SEQ + t0] =
              *(const ushort4*)pk;
        }
      } else {  // EP == 4: split-K
        if (bz == 3) {
#pragma unroll
          for (int r = 0; r < 4; r++) {
            size_t idx = (size_t)(rowb + r) * N + col;
            ((float*)outv)[idx] = acc[mi][ni][r] + bc + res[idx];
          }
        } else {
          const size_t MN = (size_t)M * N;
          float* pp = (bz == 0) ? p0 : p12 + (size_t)(bz - 1) * MN;
#pragma unroll
          for (int r = 0; r < 4; r++)
            pp[(size_t)(rowb + r) * N + col] = acc[mi][ni][r];
        }
      }
    }
  }
}

// ---------------- split-K partial reduce: out += p0 + p12[0] + p12[1] ----------------
__global__ __launch_bounds__(256) void red3(const float* __restrict__ p0,
                                            const float* __restrict__ p12,
                                            float* __restrict__ out) {
  const size_t MN4 = (size_t)4096 * 1024 / 4;
  for (size_t i = (size_t)blockIdx.x * 256 + threadIdx.x; i < MN4;
       i += (size_t)gridDim.x * 256) {
    float4 a = ((const float4*)p0)[i];
    float4 b = ((const float4*)p12)[i];
    float4 c = ((const float4*)p12)[i + MN4];
    float4 o = ((float4*)out)[i];
    o.x += a.x + b.x + c.x;
    o.y += a.y + b.y + c.y;
    o.z += a.z + b.z + c.z;
    o.w += a.w + b.w + c.w;
    ((float4*)out)[i] = o;
  }
}

// ---------------- flash attention (causal), D=64, operand-swapped ----------------
// triple-buffered K/V in LDS, counted vmcnt, ONE raw s_barrier per step.
__global__ __launch_bounds__(256) void attn_fwd(const unsigned short* __restrict__ qkv,
                                                const unsigned short* __restrict__ vt,
                                                unsigned short* __restrict__ y) {
  __shared__ __align__(16) unsigned short Ks[3][64 * 64];
  __shared__ __align__(16) unsigned short Vs[3][64 * 64];
  __shared__ __align__(16) unsigned short Ps[4 * 16 * 72];
  const int tid = threadIdx.x;
  const int wv = tid >> 6, ln = tid & 63;
  const int quad = ln >> 4, l15 = ln & 15;
  const int pair = blockIdx.x, h = blockIdx.y, b = blockIdx.z;
  unsigned short* Pw = &Ps[wv * 16 * 72];

  const unsigned short* kbase = qkv + (size_t)b * T_SEQ * 3072 + 1024 + h * HD;
  const unsigned short* vbase = vt + (size_t)(b * NH + h) * HD * T_SEQ;

  int koffs[2], voffs[2], ldst[2];
#pragma unroll
  for (int g = 0; g < 2; g++) {
    int S = wv * 128 + g * 64 + ln;
    int r = S >> 3;
    int c = (S & 7) ^ (r & 7);
    koffs[g] = r * 3072 + c * 8;
    voffs[g] = r * T_SEQ + c * 8;
    ldst[g] = wv * 1024 + g * 512;
  }

  auto stage = [&](int kt, int slot) {
#pragma unroll
    for (int g = 0; g < 2; g++) {
      gload16(kbase + (size_t)(kt * 64) * 3072 + koffs[g], &Ks[slot][ldst[g]]);
      gload16(vbase + kt * 64 + voffs[g], &Vs[slot][ldst[g]]);
    }
  };

  for (int ph = 0; ph < 2; ++ph) {
    const int qt = ph ? (31 - pair) : pair;
    const unsigned short* qp =
        qkv + (size_t)(b * T_SEQ + qt * 64 + wv * 16 + l15) * 3072 + h * HD;
    bf16x8 qf[2];
#pragma unroll
    for (int kc = 0; kc < 2; kc++) {
      ushort8 u = *(const ushort8*)(qp + kc * 32 + quad * 8);
      union { ushort8 u; bf16x8 v; } cv;
#pragma unroll
      for (int j = 0; j < 8; j++) cv.u[j] = f2b(b2f(u[j]) * 0.18033688f);
      qf[kc] = cv.v;
    }

    floatx4 o[4];
#pragma unroll
    for (int dt = 0; dt < 4; dt++) o[dt] = (floatx4)0.0f;
    float lacc = 0.0f;

    stage(0, 0);
    if (qt >= 1) stage(1, 1);

    for (int kt = 0; kt <= qt; ++kt) {
      const int slot = kt % 3;
      const bool diag = (kt == qt);
      if (kt < qt) WAITV(4); else WAITV(0);
      __builtin_amdgcn_s_barrier();
      if (kt + 2 <= qt) stage(kt + 2, (kt + 2) % 3);

      const unsigned short* Kc = Ks[slot];
      const unsigned short* Vc = Vs[slot];
      floatx4 s[4];
#pragma unroll
      for (int nt = 0; nt < 4; nt++) s[nt] = (floatx4)0.0f;
#pragma unroll
      for (int nt = 0; nt < 4; nt++)
#pragma unroll
        for (int kc = 0; kc < 2; kc++) {
          bf16x8 kf = *(const bf16x8*)
              &Kc[(nt * 16 + l15) * 64 + (((kc * 4 + quad) ^ (l15 & 7)) * 8)];
          s[nt] = mfma_bf16(kf, qf[kc], s[nt]);
        }

      float psum = 0.0f;
#pragma unroll
      for (int nt = 0; nt < 4; nt++) {
        __align__(8) unsigned short pk[4];
#pragma unroll
        for (int r = 0; r < 4; r++) {
          float sv = s[nt][r];
          if (diag && (nt * 16 + quad * 4 + r > wv * 16 + l15)) sv = -1e30f;
          float p = exp2f(sv - 12.0f);
          psum += p;
          pk[r] = f2b(p);
        }
        *(ushort4*)&Pw[l15 * 72 + nt * 16 + quad * 4] = *(const ushort4*)pk;
      }
      lacc += psum;

      bf16x8 pf0 = *(const bf16x8*)&Pw[l15 * 72 + quad * 8];
      bf16x8 pf1 = *(const bf16x8*)&Pw[l15 * 72 + 32 + quad * 8];
#pragma unroll
      for (int dt = 0; dt < 4; dt++) {
        bf16x8 vf0 = *(const bf16x8*)
            &Vc[(dt * 16 + l15) * 64 + ((quad ^ (l15 & 7)) * 8)];
        bf16x8 vf1 = *(const bf16x8*)
            &Vc[(dt * 16 + l15) * 64 + (((4 + quad) ^ (l15 & 7)) * 8)];
        o[dt] = mfma_bf16(vf0, pf0, o[dt]);
        o[dt] = mfma_bf16(vf1, pf1, o[dt]);
      }
    }

    lacc += __shfl_xor(lacc, 16, 64);
    lacc += __shfl_xor(lacc, 32, 64);
    float rinv = 1.0f / lacc;
#pragma unroll
    for (int dt = 0; dt < 4; dt++) {
      __align__(8) unsigned short ov[4];
#pragma unroll
      for (int r = 0; r < 4; r++) ov[r] = f2b(o[dt][r] * rinv);
      *(ushort4*)&y[(size_t)(b * T_SEQ + qt * 64 + wv * 16 + l15) * C_EMBD +
                    h * HD + dt * 16 + quad * 4] = *(const ushort4*)ov;
    }
  }
}

extern "C" void kernel_launch(void* const* d_in, const int* in_sizes, int n_in,
                              void* d_out, int out_size, void* d_ws, size_t ws_size,
                              hipStream_t stream) {
  (void)in_sizes; (void)n_in; (void)out_size; (void)ws_size;
  const float* x      = (const float*)d_in[0];
  const float* ln1_g  = (const float*)d_in[1];
  const float* ln1_b  = (const float*)d_in[2];
  const float* w_attn = (const float*)d_in[3];
  const float* b_attn = (const float*)d_in[4];
  const float* w_proj = (const float*)d_in[5];
  const float* b_proj = (const float*)d_in[6];
  const float* ln2_g  = (const float*)d_in[7];
  const float* ln2_b  = (const float*)d_in[8];
  const float* w_fc   = (const float*)d_in[9];
  const float* b_fc   = (const float*)d_in[10];
  const float* w_fc2  = (const float*)d_in[11];
  const float* b_fc2  = (const float*)d_in[12];
  float* out = (float*)d_out;  // also serves as x1 (post-attention residual)

  char* wsb = (char*)d_ws;
  char* ws = wsb;
  unsigned short* wat  = (unsigned short*)ws; ws += (size_t)3072 * 1024 * 2;  // [0,6M)
  unsigned short* wpt  = (unsigned short*)ws; ws += (size_t)1024 * 1024 * 2;  // [6,8M)
  unsigned short* wft  = (unsigned short*)ws; ws += (size_t)4096 * 1024 * 2;  // [8,16M)
  unsigned short* wf2t = (unsigned short*)ws; ws += (size_t)1024 * 4096 * 2;  // [16,24M) LIVE in FC2
  unsigned short* xn   = (unsigned short*)ws; ws += (size_t)4096 * 1024 * 2;  // [24,32M)
  unsigned short* qkv  = (unsigned short*)ws; ws += (size_t)4096 * 3072 * 2;  // [32,56M)
  unsigned short* yat  = (unsigned short*)ws; ws += (size_t)4096 * 1024 * 2;  // [56,64M)
  unsigned short* hbuf = (unsigned short*)ws; ws += (size_t)4096 * 4096 * 2;  // [64,96M) LIVE in FC2
  // V^T (8 MB) aliases hbuf: vt live QKV-gemm -> attn; hbuf live FC -> FC2.
  unsigned short* vt = hbuf;
  // FC2 split-K partials alias regions dead by FC2 time:
  // p0  (16MB) over wat+wpt+wft; p12 (32MB) over xn+qkv.
  float* p0  = (float*)wsb;
  float* p12 = (float*)(wsb + (size_t)24 * 1024 * 1024);

  wtrans<<<dim3(3072 / 32, 1024 / 32), 256, 0, stream>>>(w_attn, wat, 1024, 3072);
  wtrans<<<dim3(1024 / 32, 1024 / 32), 256, 0, stream>>>(w_proj, wpt, 1024, 1024);
  wtrans<<<dim3(4096 / 32, 1024 / 32), 256, 0, stream>>>(w_fc, wft, 1024, 4096);
  wtrans<<<dim3(1024 / 32, 4096 / 32), 256, 0, stream>>>(w_fc2, wf2t, 4096, 1024);

  ln_fwd<<<4096, 256, 0, stream>>>(x, ln1_g, ln1_b, xn);
  gemm128<3><<<dim3(3072 / 128, 4096 / 128), 256, 0, stream>>>(
      xn, wat, b_attn, nullptr, qkv, vt, nullptr, nullptr, 4096, 3072, 1024, 1024);
  attn_fwd<<<dim3(16, NH, 2), 256, 0, stream>>>(qkv, vt, yat);
  gemm128<1><<<dim3(1024 / 128, 4096 / 128), 256, 0, stream>>>(
      yat, wpt, b_proj, x, out, nullptr, nullptr, nullptr, 4096, 1024, 1024, 1024);
  ln_fwd<<<4096, 256, 0, stream>>>(out, ln2_g, ln2_b, xn);
  gemm128<2><<<dim3(4096 / 128, 4096 / 128), 256, 0, stream>>>(
      xn, wft, b_fc, nullptr, hbuf, nullptr, nullptr, nullptr, 4096, 4096, 1024, 1024);
  gemm128<4><<<dim3(1024 / 128, 4096 / 128, 4), 256, 0, stream>>>(
      hbuf, wf2t, b_fc2, out, out, nullptr, p0, p12, 4096, 1024, 4096, 1024);
  red3<<<2048, 256, 0, stream>>>(p0, p12, out);
}